// Round 1
// baseline (4451.390 us; speedup 1.0000x reference)
//
#include <hip/hip_runtime.h>

#define FDIM 128

// Phase 1: segment scatter-add. One thread per float4 of a node row.
// 32 threads cover one node's 128 features; reads fully coalesced (16B/lane);
// atomics go to consecutive addresses of the (L2-resident) pooled buffer.
__global__ __launch_bounds__(256) void seg_sum_kernel(
    const float* __restrict__ h, const int* __restrict__ seg,
    float* __restrict__ pooled, int n4)
{
    int gid = blockIdx.x * 256 + threadIdx.x;
    if (gid >= n4) return;
    int node = gid >> 5;   // 32 threads per node
    int q    = gid & 31;   // which float4 of the row
    float4 v = reinterpret_cast<const float4*>(h)[(size_t)node * 32 + q];
    int s = seg[node];
    float* dst = pooled + (size_t)s * FDIM + q * 4;
    atomicAdd(dst + 0, v.x);
    atomicAdd(dst + 1, v.y);
    atomicAdd(dst + 2, v.z);
    atomicAdd(dst + 3, v.w);
}

// Phase 2: y[g] = tanh(pooled[g,:] @ W1 + b1) @ W2 + b2
// W1 (64KB) staged in LDS. 256 threads = 8 groups of 32 lanes; each group does
// one graph: lane holds 4 outputs j=lane*4..lane*4+3 (float4 ds_read_b128 on
// W1, conflict-free), pooled row lives in the group's registers and is
// broadcast with __shfl width=32.
__global__ __launch_bounds__(256) void mlp_kernel(
    const float* __restrict__ pooled,
    const float* __restrict__ W1, const float* __restrict__ b1,
    const float* __restrict__ W2, const float* __restrict__ b2,
    float* __restrict__ out, int G)
{
    __shared__ float w1s[FDIM * FDIM];  // 64 KB
    for (int i = threadIdx.x; i < FDIM * FDIM; i += 256) w1s[i] = W1[i];

    int grp  = threadIdx.x >> 5;
    int lane = threadIdx.x & 31;
    float  b2v = b2[0];
    float4 bb  = reinterpret_cast<const float4*>(b1)[lane];
    float4 ww  = reinterpret_cast<const float4*>(W2)[lane];
    __syncthreads();

    const float4* wrow = reinterpret_cast<const float4*>(w1s);

    for (int gbase = blockIdx.x * 8; gbase < G; gbase += gridDim.x * 8) {
        int g = gbase + grp;
        float4 myrow = make_float4(0.f, 0.f, 0.f, 0.f);
        if (g < G)
            myrow = reinterpret_cast<const float4*>(pooled + (size_t)g * FDIM)[lane];

        float4 acc = make_float4(0.f, 0.f, 0.f, 0.f);
        #pragma unroll 8
        for (int l = 0; l < 32; ++l) {
            // broadcast row elements 4l..4l+3 from lane l of this 32-group
            float vx = __shfl(myrow.x, l, 32);
            float vy = __shfl(myrow.y, l, 32);
            float vz = __shfl(myrow.z, l, 32);
            float vw = __shfl(myrow.w, l, 32);
            float4 w0 = wrow[(l * 4 + 0) * 32 + lane];
            float4 w1 = wrow[(l * 4 + 1) * 32 + lane];
            float4 w2 = wrow[(l * 4 + 2) * 32 + lane];
            float4 w3 = wrow[(l * 4 + 3) * 32 + lane];
            acc.x = fmaf(vx, w0.x, acc.x); acc.y = fmaf(vx, w0.y, acc.y);
            acc.z = fmaf(vx, w0.z, acc.z); acc.w = fmaf(vx, w0.w, acc.w);
            acc.x = fmaf(vy, w1.x, acc.x); acc.y = fmaf(vy, w1.y, acc.y);
            acc.z = fmaf(vy, w1.z, acc.z); acc.w = fmaf(vy, w1.w, acc.w);
            acc.x = fmaf(vz, w2.x, acc.x); acc.y = fmaf(vz, w2.y, acc.y);
            acc.z = fmaf(vz, w2.z, acc.z); acc.w = fmaf(vz, w2.w, acc.w);
            acc.x = fmaf(vw, w3.x, acc.x); acc.y = fmaf(vw, w3.y, acc.y);
            acc.z = fmaf(vw, w3.z, acc.z); acc.w = fmaf(vw, w3.w, acc.w);
        }

        float t = tanhf(acc.x + bb.x) * ww.x
                + tanhf(acc.y + bb.y) * ww.y
                + tanhf(acc.z + bb.z) * ww.z
                + tanhf(acc.w + bb.w) * ww.w;

        // reduce the 32 lanes of this group
        for (int off = 16; off > 0; off >>= 1)
            t += __shfl_down(t, off, 32);

        if (lane == 0 && g < G) out[g] = t + b2v;
    }
}

extern "C" void kernel_launch(void* const* d_in, const int* in_sizes, int n_in,
                              void* d_out, int out_size, void* d_ws, size_t ws_size,
                              hipStream_t stream) {
    const float* h   = (const float*)d_in[0];
    const int*   seg = (const int*)d_in[1];
    // d_in[2] = num_graphs scalar (device mem) — G derived from out_size instead
    const float* W1  = (const float*)d_in[3];
    const float* b1  = (const float*)d_in[4];
    const float* W2  = (const float*)d_in[5];
    const float* b2  = (const float*)d_in[6];
    float* out = (float*)d_out;

    int N = in_sizes[0] / FDIM;   // 2,000,000
    int G = out_size;             // 50,000 (OUT=1)

    float* pooled = (float*)d_ws; // G*FDIM floats = 25.6 MB scratch
    hipMemsetAsync(pooled, 0, (size_t)G * FDIM * sizeof(float), stream);

    int n4 = N * 32;  // one thread per float4
    int grid1 = (n4 + 255) / 256;
    seg_sum_kernel<<<grid1, 256, 0, stream>>>(h, seg, pooled, n4);

    mlp_kernel<<<1024, 256, 0, stream>>>(pooled, W1, b1, W2, b2, out, G);
}